// Round 4
// baseline (643.647 us; speedup 1.0000x reference)
//
#include <hip/hip_runtime.h>
#include <hip/hip_bf16.h>
#include <math.h>

#define B_N 32
#define S_LEN 4096
#define NTOK (B_N * S_LEN)   // 131072
#define EMB 256
#define NCODE 512
#define WB_STRIDE 98304      // per-batch weight entries (bf16)

typedef __attribute__((ext_vector_type(8))) short short8v;   // 8 bf16 = 4 VGPRs
typedef __attribute__((ext_vector_type(4))) float float4v;

__device__ inline ushort f2b(float v) {
    union { __hip_bfloat16 h; ushort u; } cv;
    cv.h = __float2bfloat16(v);   // RNE
    return cv.u;
}
__device__ inline float b2f(ushort u) {
    union { ushort u2[2]; float f; } cv;
    cv.u2[0] = 0; cv.u2[1] = u;
    return cv.f;
}
__device__ inline short8v pack8(float4 a, float4 b) {
    short8v r;
    r[0] = (short)f2b(a.x); r[1] = (short)f2b(a.y);
    r[2] = (short)f2b(a.z); r[3] = (short)f2b(a.w);
    r[4] = (short)f2b(b.x); r[5] = (short)f2b(b.y);
    r[6] = (short)f2b(b.z); r[7] = (short)f2b(b.w);
    return r;
}

// ---- ws layout (bytes) ----
constexpr size_t WSB_W   = 0;         // ushort[3145728] generated weights (bf16)
constexpr size_t WSB_CB  = 6291456;   // ushort[131072] codebook bf16
constexpr size_t WSB_CBN = 6553600;   // float[512] codebook sq-norms
constexpr size_t WSB_ACC = 6555648;   // float[513]: [0]=sse, [1..512]=hist

// ---- out layout (floats) ----
constexpr size_t OUT_SCAL = 33554432; // loss, perplexity
constexpr size_t OUT_XR   = 33554434; // x_recon fp32

// ================= prep: weight gen (blocks 0..383) + codebook prep (384..385) =========
struct WgenP {
    const float* bw[6]; const float* aw[6]; const float* ab[6];
    int loff[6]; int bstart[7];
};

__global__ __launch_bounds__(256)
void prep_kernel(WgenP p, const float* __restrict__ adapt, ushort* __restrict__ wout,
                 const float* __restrict__ cb, float* __restrict__ cbn,
                 ushort* __restrict__ cbbf)
{
    int tid = threadIdx.x;
    if (blockIdx.x >= 384) {   // codebook: norms fp32 + bf16 copy
        int c = (blockIdx.x - 384) * 256 + tid;
        const float4* c4 = reinterpret_cast<const float4*>(cb) + (size_t)c * 64;
        ushort4* o4 = reinterpret_cast<ushort4*>(cbbf) + (size_t)c * 64;
        float s = 0.f;
#pragma unroll 8
        for (int q = 0; q < 64; ++q) {
            float4 v = c4[q];
            s += v.x*v.x + v.y*v.y + v.z*v.z + v.w*v.w;
            o4[q] = make_ushort4(f2b(v.x), f2b(v.y), f2b(v.z), f2b(v.w));
        }
        cbn[c] = s;
        return;
    }
    __shared__ float ad[B_N * 64];
    for (int i = tid; i < B_N * 64; i += 256) ad[i] = adapt[i];
    __syncthreads();
    int blk = blockIdx.x;
    int l = 0;
    while (l < 5 && blk >= p.bstart[l + 1]) ++l;
    int r = (blk - p.bstart[l]) * 256 + tid;

    float a[64];
    const float4* aw4 = reinterpret_cast<const float4*>(p.aw[l] + (size_t)r * 64);
#pragma unroll
    for (int q = 0; q < 16; ++q) {
        float4 v = aw4[q];
        a[4*q] = v.x; a[4*q+1] = v.y; a[4*q+2] = v.z; a[4*q+3] = v.w;
    }
    float abr = p.ab[l][r], bwr = p.bw[l][r];
    int loff = p.loff[l];
    for (int b2 = 0; b2 < B_N; ++b2) {
        const float* adp = &ad[b2 * 64];
        float s0 = 0.f, s1 = 0.f, s2 = 0.f, s3 = 0.f;
#pragma unroll
        for (int j = 0; j < 64; j += 4) {
            s0 += a[j]   * adp[j];
            s1 += a[j+1] * adp[j+1];
            s2 += a[j+2] * adp[j+2];
            s3 += a[j+3] * adp[j+3];
        }
        float s = ((s0 + s1) + (s2 + s3)) + abr;
        wout[(size_t)b2 * WB_STRIDE + loff + r] = f2b(bwr + s);
    }
}

// ================= fully fused VQ-VAE: one wave owns 32 tokens end-to-end ==============
// 64-thread blocks, NO __syncthreads. Weights/codebook B-frags direct from L2.
// Per-wave LDS: RA 16896 B (h0[32][72] -> zb[32][264] -> h4[32][72]),
//               RB 8704 B (h1[32][136] -> h3[32][136]), midx 128 B.
__global__ __launch_bounds__(64)
void vqvae_fused(const float* __restrict__ x, const ushort* __restrict__ wbf,
                 const float* __restrict__ bb0, const float* __restrict__ bb1,
                 const float* __restrict__ bb2, const float* __restrict__ bb3,
                 const float* __restrict__ bb4, const float* __restrict__ bb5,
                 const ushort* __restrict__ cbbf, const float* __restrict__ cbf,
                 const float* __restrict__ cbn,
                 float* __restrict__ zq, float* __restrict__ xr,
                 float* __restrict__ accg)
{
    __shared__ __align__(16) char smem[25728];
    ushort* RA = reinterpret_cast<ushort*>(smem);           // h0 / zb / h4
    ushort* RB = reinterpret_cast<ushort*>(smem + 16896);   // h1 / h3
    int*  midx = reinterpret_cast<int*>(smem + 25600);      // 32 ints

    const int lane = threadIdx.x;
    const int r16 = lane & 15, g = lane >> 4;
    const size_t tb = (size_t)blockIdx.x * 32;              // global token base
    const int b = (int)(tb >> 12);                          // batch (4096 tok/batch)
    const ushort* wb = wbf + (size_t)b * WB_STRIDE;

    // ---- stage x A-frags (fp32 -> bf16, straight from global)
    short8v ax[2][4];
#pragma unroll
    for (int mt = 0; mt < 2; ++mt)
#pragma unroll
        for (int ks = 0; ks < 4; ++ks) {
            const float4* p4 = reinterpret_cast<const float4*>(
                x + (tb + mt*16 + r16) * 128 + ks*32 + g*8);
            ax[mt][ks] = pack8(p4[0], p4[1]);
        }

    // ---- e0: 128 -> 64, relu -> h0[32][72]
    ushort* h0 = RA;
#pragma unroll
    for (int nt = 0; nt < 4; ++nt) {
        short8v bf[4];
#pragma unroll
        for (int ks = 0; ks < 4; ++ks)
            bf[ks] = *reinterpret_cast<const short8v*>(
                wb + (size_t)(nt*16 + r16) * 128 + ks*32 + g*8);
        float bias = bb0[nt*16 + r16];
#pragma unroll
        for (int mt = 0; mt < 2; ++mt) {
            float4v acc = (float4v){0.f, 0.f, 0.f, 0.f};
#pragma unroll
            for (int ks = 0; ks < 4; ++ks)
                acc = __builtin_amdgcn_mfma_f32_16x16x32_bf16(ax[mt][ks], bf[ks], acc, 0, 0, 0);
#pragma unroll
            for (int reg = 0; reg < 4; ++reg)
                h0[(mt*16 + g*4 + reg) * 72 + nt*16 + r16] =
                    f2b(fmaxf(acc[reg] + bias, 0.f));
        }
    }

    // ---- e1: 64 -> 128, relu -> h1[32][136]
    short8v ah[2][2];
#pragma unroll
    for (int mt = 0; mt < 2; ++mt)
#pragma unroll
        for (int ks = 0; ks < 2; ++ks)
            ah[mt][ks] = *reinterpret_cast<const short8v*>(
                &h0[(mt*16 + r16) * 72 + ks*32 + g*8]);
    ushort* h1 = RB;
    {
        const ushort* w1 = wb + 8192;
#pragma unroll
        for (int nt = 0; nt < 8; ++nt) {
            short8v bf[2];
#pragma unroll
            for (int ks = 0; ks < 2; ++ks)
                bf[ks] = *reinterpret_cast<const short8v*>(
                    w1 + (size_t)(nt*16 + r16) * 64 + ks*32 + g*8);
            float bias = bb1[nt*16 + r16];
#pragma unroll
            for (int mt = 0; mt < 2; ++mt) {
                float4v acc = (float4v){0.f, 0.f, 0.f, 0.f};
#pragma unroll
                for (int ks = 0; ks < 2; ++ks)
                    acc = __builtin_amdgcn_mfma_f32_16x16x32_bf16(ah[mt][ks], bf[ks], acc, 0, 0, 0);
#pragma unroll
                for (int reg = 0; reg < 4; ++reg)
                    h1[(mt*16 + g*4 + reg) * 136 + nt*16 + r16] =
                        f2b(fmaxf(acc[reg] + bias, 0.f));
            }
        }
    }

    // ---- e2: 128 -> 256, none -> zb[32][264] (overlays dead h0)
    short8v a2[2][4];
#pragma unroll
    for (int mt = 0; mt < 2; ++mt)
#pragma unroll
        for (int ks = 0; ks < 4; ++ks)
            a2[mt][ks] = *reinterpret_cast<const short8v*>(
                &h1[(mt*16 + r16) * 136 + ks*32 + g*8]);
    ushort* zb = RA;
    {
        const ushort* w2 = wb + 16384;
#pragma unroll
        for (int nt = 0; nt < 16; ++nt) {
            short8v bf[4];
#pragma unroll
            for (int ks = 0; ks < 4; ++ks)
                bf[ks] = *reinterpret_cast<const short8v*>(
                    w2 + (size_t)(nt*16 + r16) * 128 + ks*32 + g*8);
            float bias = bb2[nt*16 + r16];
#pragma unroll
            for (int mt = 0; mt < 2; ++mt) {
                float4v acc = (float4v){0.f, 0.f, 0.f, 0.f};
#pragma unroll
                for (int ks = 0; ks < 4; ++ks)
                    acc = __builtin_amdgcn_mfma_f32_16x16x32_bf16(a2[mt][ks], bf[ks], acc, 0, 0, 0);
#pragma unroll
                for (int reg = 0; reg < 4; ++reg)
                    zb[(mt*16 + g*4 + reg) * 264 + nt*16 + r16] = f2b(acc[reg] + bias);
            }
        }
    }

    // ---- VQ: scan 512 codes, argmin of ||e||^2 - 2*(z.e)  (||z||^2 token-const)
    short8v az[2][8];
#pragma unroll
    for (int mt = 0; mt < 2; ++mt)
#pragma unroll
        for (int ks = 0; ks < 8; ++ks)
            az[mt][ks] = *reinterpret_cast<const short8v*>(
                &zb[(mt*16 + r16) * 264 + ks*32 + g*8]);

    float mv[2][4] = {{1e30f,1e30f,1e30f,1e30f},{1e30f,1e30f,1e30f,1e30f}};
    int   mi[2][4] = {{0,0,0,0},{0,0,0,0}};
#pragma unroll 2
    for (int ct = 0; ct < 32; ++ct) {
        short8v bf[8];
#pragma unroll
        for (int ks = 0; ks < 8; ++ks)
            bf[ks] = *reinterpret_cast<const short8v*>(
                cbbf + (size_t)(ct*16 + r16) * 256 + ks*32 + g*8);
        // 4 independent accumulation chains (2 m-tiles x 2 half-K) for ILP
        float4v d0a = (float4v){0.f,0.f,0.f,0.f}, d0b = d0a, d1a = d0a, d1b = d0a;
#pragma unroll
        for (int ks = 0; ks < 4; ++ks) {
            d0a = __builtin_amdgcn_mfma_f32_16x16x32_bf16(az[0][ks],   bf[ks],   d0a, 0, 0, 0);
            d0b = __builtin_amdgcn_mfma_f32_16x16x32_bf16(az[0][ks+4], bf[ks+4], d0b, 0, 0, 0);
            d1a = __builtin_amdgcn_mfma_f32_16x16x32_bf16(az[1][ks],   bf[ks],   d1a, 0, 0, 0);
            d1b = __builtin_amdgcn_mfma_f32_16x16x32_bf16(az[1][ks+4], bf[ks+4], d1b, 0, 0, 0);
        }
        float cn = cbn[ct*16 + r16];
        int c = ct*16 + r16;
#pragma unroll
        for (int reg = 0; reg < 4; ++reg) {
            float dd0 = cn - 2.0f * (d0a[reg] + d0b[reg]);
            if (dd0 < mv[0][reg]) { mv[0][reg] = dd0; mi[0][reg] = c; }
            float dd1 = cn - 2.0f * (d1a[reg] + d1b[reg]);
            if (dd1 < mv[1][reg]) { mv[1][reg] = dd1; mi[1][reg] = c; }
        }
    }
    // butterfly over 16 code-lanes; lex (val, idx) min == first-index argmin
#pragma unroll
    for (int m = 1; m <= 8; m <<= 1) {
#pragma unroll
        for (int mt = 0; mt < 2; ++mt)
#pragma unroll
            for (int reg = 0; reg < 4; ++reg) {
                float ov = __shfl_xor(mv[mt][reg], m);
                int   oi = __shfl_xor(mi[mt][reg], m);
                if (ov < mv[mt][reg] || (ov == mv[mt][reg] && oi < mi[mt][reg])) {
                    mv[mt][reg] = ov; mi[mt][reg] = oi;
                }
            }
    }
    if (r16 == 0) {
#pragma unroll
        for (int mt = 0; mt < 2; ++mt)
#pragma unroll
            for (int reg = 0; reg < 4; ++reg)
                midx[mt*16 + g*4 + reg] = mi[mt][reg];
    }
    if (lane < 32) atomicAdd(&accg[1 + midx[lane]], 1.0f);

    // ---- epilogue: z_q = z + (q - z) (bf16 z, fp32 q), sse
    float lsse = 0.f;
    {
        float4* zq4 = reinterpret_cast<float4*>(zq) + tb * 64;
        const float4* cf4 = reinterpret_cast<const float4*>(cbf);
#pragma unroll
        for (int it = 0; it < 32; ++it) {
            int slot = lane + it * 64;
            int t = slot >> 6, k4 = slot & 63;
            float4 q = cf4[(size_t)midx[t] * 64 + k4];
            ushort4 zu = *reinterpret_cast<const ushort4*>(&zb[t * 264 + 4 * k4]);
            float zx = b2f(zu.x), zy = b2f(zu.y), zz = b2f(zu.z), zw = b2f(zu.w);
            float dx = q.x - zx, dy = q.y - zy, dz = q.z - zz, dw = q.w - zw;
            lsse += dx*dx + dy*dy + dz*dz + dw*dw;
            zq4[slot] = make_float4(zx + dx, zy + dy, zz + dz, zw + dw);
        }
    }
#pragma unroll
    for (int m = 1; m <= 32; m <<= 1) lsse += __shfl_xor(lsse, m);
    if (lane == 0) atomicAdd(&accg[0], lsse);

    // ---- d0: 256 -> 128, relu; A = gathered q (bf16) -> h3[32][136]
    short8v aq[2][8];
#pragma unroll
    for (int mt = 0; mt < 2; ++mt) {
        const ushort* qrow = cbbf + (size_t)midx[mt*16 + r16] * 256;
#pragma unroll
        for (int ks = 0; ks < 8; ++ks)
            aq[mt][ks] = *reinterpret_cast<const short8v*>(qrow + ks*32 + g*8);
    }
    ushort* h3 = RB;
    {
        const ushort* wD = wb + 49152;
#pragma unroll
        for (int nt = 0; nt < 8; ++nt) {
            short8v bf[8];
#pragma unroll
            for (int ks = 0; ks < 8; ++ks)
                bf[ks] = *reinterpret_cast<const short8v*>(
                    wD + (size_t)(nt*16 + r16) * 256 + ks*32 + g*8);
            float bias = bb3[nt*16 + r16];
#pragma unroll
            for (int mt = 0; mt < 2; ++mt) {
                float4v aa = (float4v){0.f,0.f,0.f,0.f}, ab2 = aa;
#pragma unroll
                for (int ks = 0; ks < 4; ++ks) {
                    aa  = __builtin_amdgcn_mfma_f32_16x16x32_bf16(aq[mt][ks],   bf[ks],   aa,  0, 0, 0);
                    ab2 = __builtin_amdgcn_mfma_f32_16x16x32_bf16(aq[mt][ks+4], bf[ks+4], ab2, 0, 0, 0);
                }
#pragma unroll
                for (int reg = 0; reg < 4; ++reg)
                    h3[(mt*16 + g*4 + reg) * 136 + nt*16 + r16] =
                        f2b(fmaxf(aa[reg] + ab2[reg] + bias, 0.f));
            }
        }
    }

    // ---- d1: 128 -> 64, relu -> h4[32][72] (overlays dead zb)
    short8v a3[2][4];
#pragma unroll
    for (int mt = 0; mt < 2; ++mt)
#pragma unroll
        for (int ks = 0; ks < 4; ++ks)
            a3[mt][ks] = *reinterpret_cast<const short8v*>(
                &h3[(mt*16 + r16) * 136 + ks*32 + g*8]);
    ushort* h4 = RA;
    {
        const ushort* wD = wb + 81920;
#pragma unroll
        for (int nt = 0; nt < 4; ++nt) {
            short8v bf[4];
#pragma unroll
            for (int ks = 0; ks < 4; ++ks)
                bf[ks] = *reinterpret_cast<const short8v*>(
                    wD + (size_t)(nt*16 + r16) * 128 + ks*32 + g*8);
            float bias = bb4[nt*16 + r16];
#pragma unroll
            for (int mt = 0; mt < 2; ++mt) {
                float4v acc = (float4v){0.f,0.f,0.f,0.f};
#pragma unroll
                for (int ks = 0; ks < 4; ++ks)
                    acc = __builtin_amdgcn_mfma_f32_16x16x32_bf16(a3[mt][ks], bf[ks], acc, 0, 0, 0);
#pragma unroll
                for (int reg = 0; reg < 4; ++reg)
                    h4[(mt*16 + g*4 + reg) * 72 + nt*16 + r16] =
                        f2b(fmaxf(acc[reg] + bias, 0.f));
            }
        }
    }

    // ---- d2: 64 -> 128, sigmoid -> x_recon (direct C-layout stores)
    short8v a4[2][2];
#pragma unroll
    for (int mt = 0; mt < 2; ++mt)
#pragma unroll
        for (int ks = 0; ks < 2; ++ks)
            a4[mt][ks] = *reinterpret_cast<const short8v*>(
                &h4[(mt*16 + r16) * 72 + ks*32 + g*8]);
    {
        const ushort* wD = wb + 90112;
#pragma unroll
        for (int nt = 0; nt < 8; ++nt) {
            short8v bf[2];
#pragma unroll
            for (int ks = 0; ks < 2; ++ks)
                bf[ks] = *reinterpret_cast<const short8v*>(
                    wD + (size_t)(nt*16 + r16) * 64 + ks*32 + g*8);
            float bias = bb5[nt*16 + r16];
#pragma unroll
            for (int mt = 0; mt < 2; ++mt) {
                float4v acc = (float4v){0.f,0.f,0.f,0.f};
#pragma unroll
                for (int ks = 0; ks < 2; ++ks)
                    acc = __builtin_amdgcn_mfma_f32_16x16x32_bf16(a4[mt][ks], bf[ks], acc, 0, 0, 0);
#pragma unroll
                for (int reg = 0; reg < 4; ++reg) {
                    float v = acc[reg] + bias;
                    xr[(tb + mt*16 + g*4 + reg) * 128 + nt*16 + r16] =
                        1.0f / (1.0f + expf(-v));
                }
            }
        }
    }
}

// ================= finalize scalars =================
__global__ __launch_bounds__(512)
void finalize_kernel(const float* __restrict__ acc, float* __restrict__ out_scal)
{
    __shared__ float red[512];
    int tid = threadIdx.x;
    float p = acc[1 + tid] * (1.0f / (float)NTOK);
    red[tid] = p * logf(p + 1e-10f);
    __syncthreads();
    for (int s = 256; s > 0; s >>= 1) {
        if (tid < s) red[tid] += red[tid + s];
        __syncthreads();
    }
    if (tid == 0) {
        out_scal[0] = 1.25f * (acc[0] * (1.0f / 33554432.0f)); // q_latent + 0.25*e_latent
        out_scal[1] = expf(-red[0]);
    }
}

// ================= launch =================
extern "C" void kernel_launch(void* const* d_in, const int* in_sizes, int n_in,
                              void* d_out, int out_size, void* d_ws, size_t ws_size,
                              hipStream_t stream)
{
    (void)in_sizes; (void)n_in; (void)out_size; (void)ws_size;
    const float* x     = (const float*)d_in[0];
    const float* adapt = (const float*)d_in[1];
    const float* bw[6]  = {(const float*)d_in[2],  (const float*)d_in[6],  (const float*)d_in[10],
                           (const float*)d_in[14], (const float*)d_in[18], (const float*)d_in[22]};
    const float* bbp[6] = {(const float*)d_in[3],  (const float*)d_in[7],  (const float*)d_in[11],
                           (const float*)d_in[15], (const float*)d_in[19], (const float*)d_in[23]};
    const float* aw[6]  = {(const float*)d_in[4],  (const float*)d_in[8],  (const float*)d_in[12],
                           (const float*)d_in[16], (const float*)d_in[20], (const float*)d_in[24]};
    const float* ab[6]  = {(const float*)d_in[5],  (const float*)d_in[9],  (const float*)d_in[13],
                           (const float*)d_in[17], (const float*)d_in[21], (const float*)d_in[25]};
    const float* cb = (const float*)d_in[26];

    char*   wsb  = (char*)d_ws;
    ushort* wbf  = (ushort*)(wsb + WSB_W);
    ushort* cbbf = (ushort*)(wsb + WSB_CB);
    float*  cbn  = (float*) (wsb + WSB_CBN);
    float*  acc  = (float*) (wsb + WSB_ACC);

    float*  out  = (float*)d_out;
    float*  zf   = out;              // z_q fp32
    float*  scal = out + OUT_SCAL;
    float*  xr   = out + OUT_XR;     // x_recon fp32

    hipMemsetAsync(acc, 0, 513 * sizeof(float), stream);

    WgenP p;
    const int loff[6]   = {0, 8192, 16384, 49152, 81920, 90112};
    const int bstart[7] = {0, 32, 64, 192, 320, 352, 384};
    for (int l = 0; l < 6; ++l) {
        p.bw[l] = bw[l]; p.aw[l] = aw[l]; p.ab[l] = ab[l]; p.loff[l] = loff[l];
    }
    for (int i = 0; i < 7; ++i) p.bstart[i] = bstart[i];

    prep_kernel<<<386, 256, 0, stream>>>(p, adapt, wbf, cb, cbn, cbbf);
    vqvae_fused<<<NTOK / 32, 64, 0, stream>>>(x, wbf,
                                              bbp[0], bbp[1], bbp[2], bbp[3], bbp[4], bbp[5],
                                              cbbf, cb, cbn, zf, xr, acc);
    finalize_kernel<<<1, 512, 0, stream>>>(acc, scal);
}